// Round 4
// baseline (211.233 us; speedup 1.0000x reference)
//
#include <hip/hip_runtime.h>
#include <math.h>

// Problem constants (match reference file)
#define NN   8192   // nodes
#define DF   64     // feature dim
#define KK   16     // k samples
#define DEG  32     // max neighbors
#define MAXNBR (DEG + 1)     // self + neighbors
#define SLOTS 3              // 256 threads * 3 >= 33*16 = 528 candidates
#define SCAN_BLOCKS 2048     // 2048*256 threads; 16.7M uint4 / 524288 = 32 exact

// ws layout: [0, 8192) ints = per-row neighbor count; then 8192*32 ints = lists
#define WS_CNT(ws)  ((int*)(ws))
#define WS_NBR(ws)  (((int*)(ws)) + NN)

// ---- kernel 1: stream the 256 MB adjacency, compact nonzeros into lists ----
__global__ __launch_bounds__(256, 8)
void adj_scan_kernel(const uint4* __restrict__ a4,
                     int* __restrict__ cnt, int* __restrict__ nbr)
{
    const int tid    = blockIdx.x * 256 + threadIdx.x;
    const int stride = SCAN_BLOCKS * 256;
    // total uint4s = NN*NN/4 = 16777216 = 32 * stride; batch 4 per iter
    for (int p = tid; p < NN * NN / 4; p += 4 * stride) {
        uint4 v[4];
        #pragma unroll
        for (int u = 0; u < 4; ++u) v[u] = a4[p + u * stride];   // 4 loads in flight
        #pragma unroll
        for (int u = 0; u < 4; ++u) {
            if ((v[u].x | v[u].y | v[u].z | v[u].w) != 0u) {     // 1.0f == 0x3F800000
                const int base = 4 * (p + u * stride);
                const unsigned wv[4] = {v[u].x, v[u].y, v[u].z, v[u].w};
                #pragma unroll
                for (int c = 0; c < 4; ++c) {
                    if (wv[c] != 0u) {
                        int lin = base + c;
                        int row = lin >> 13;          // / NN
                        int col = lin & (NN - 1);
                        int s = atomicAdd(&cnt[row], 1);
                        if (s < DEG) nbr[row * DEG + s] = col;
                    }
                }
            }
        }
    }
}

// ---- kernel 2: one block (4 waves) per node: gather, dedup, sims, top-K ----
__global__ __launch_bounds__(256, 4)
void select_kernel(const float* __restrict__ x,
                   const int*   __restrict__ cs,
                   const int*   __restrict__ cnt,
                   const int*   __restrict__ nbr,
                   int*         __restrict__ out)
{
    const int i    = blockIdx.x;           // node id
    const int t    = threadIdx.x;
    const int w    = t >> 6;
    const int lane = t & 63;

    __shared__ unsigned mask[NN / 32];                 // 1 KB dedup bitmap
    __shared__ int nbrs[MAXNBR];
    __shared__ unsigned long long wkeys[4 * KK];       // per-wave top-16s
    __shared__ int nu_sh;

    // ---- phase A: init ----
    for (int m = t; m < NN / 32; m += 256) mask[m] = 0u;
    if (t == 0) { nbrs[0] = i; nu_sh = 0; }
    const int c = min(cnt[i], DEG);
    if (t < c) nbrs[1 + t] = nbr[i * DEG + t];
    __syncthreads();                                   // barrier 1

    const int total = (c + 1) * KK;                    // <= 528
    const float* __restrict__ xr = x + (size_t)i * DF; // block-uniform -> SGPRs

    // ---- phase B: gather candidates, dedup via shared bitmap ----
    int  vals[SLOTS];
    bool valid[SLOTS];
    #pragma unroll
    for (int r = 0; r < SLOTS; ++r) {
        valid[r] = false;
        vals[r]  = 0;
        int q = t + 256 * r;
        if (q < total) {
            int node = nbrs[q >> 4];
            int v = cs[(size_t)node * KK + (q & 15)];
            unsigned bit = 1u << (v & 31);
            unsigned old = atomicOr(&mask[v >> 5], bit);
            if (!(old & bit)) { valid[r] = true; vals[r] = v; }
        }
    }

    // unique count: wave sum -> LDS add
    int myc = 0;
    #pragma unroll
    for (int r = 0; r < SLOTS; ++r) myc += valid[r] ? 1 : 0;
    #pragma unroll
    for (int off = 32; off; off >>= 1) myc += __shfl_xor(myc, off);
    if (lane == 0) atomicAdd(&nu_sh, myc);

    // ---- phase C: sims (strict sequential FMA chain — bit-matches BLAS k-loop) ----
    unsigned long long keys[SLOTS];
    #pragma unroll
    for (int r = 0; r < SLOTS; ++r) {
        unsigned long long key = 0ULL;
        if (valid[r]) {
            const float4* xc4 = reinterpret_cast<const float4*>(x + (size_t)vals[r] * DF);
            float4 xv[DF / 4];
            #pragma unroll
            for (int d4 = 0; d4 < DF / 4; ++d4) xv[d4] = xc4[d4];
            float acc = 0.f;
            #pragma unroll
            for (int d4 = 0; d4 < DF / 4; ++d4) {
                acc = fmaf(xr[4 * d4 + 0], xv[d4].x, acc);
                acc = fmaf(xr[4 * d4 + 1], xv[d4].y, acc);
                acc = fmaf(xr[4 * d4 + 2], xv[d4].z, acc);
                acc = fmaf(xr[4 * d4 + 3], xv[d4].w, acc);
            }
            unsigned fb = __float_as_uint(acc);
            fb = (fb & 0x80000000u) ? ~fb : (fb | 0x80000000u);   // order-preserving
            key = ((unsigned long long)fb << 13) |
                  (unsigned long long)(unsigned)(8191 - vals[r]);
        }
        keys[r] = key;
    }

    // ---- phase D: per-wave top-16 (pure shuffles, no barriers) ----
    for (int j = 0; j < KK; ++j) {
        unsigned long long m = 0ULL;
        #pragma unroll
        for (int r = 0; r < SLOTS; ++r) m = keys[r] > m ? keys[r] : m;
        #pragma unroll
        for (int off = 32; off; off >>= 1) {
            unsigned long long o = __shfl_xor(m, off);
            m = o > m ? o : m;
        }
        if (lane == 0) wkeys[w * KK + j] = m;
        #pragma unroll
        for (int r = 0; r < SLOTS; ++r)
            if (keys[r] == m) keys[r] = 0ULL;   // values unique -> safe clear
    }
    __syncthreads();                                   // barrier 2

    // ---- phase E: wave 0 merges 64 keys; 16 shuffle-argmax rounds ----
    const int nu = nu_sh;
    if (nu >= KK) {
        if (w == 0) {
            unsigned long long k = wkeys[lane];        // 64 keys, one per lane
            int myout = 0;
            for (int j = 0; j < KK; ++j) {
                unsigned long long m = k;
                #pragma unroll
                for (int off = 32; off; off >>= 1) {
                    unsigned long long o = __shfl_xor(m, off);
                    m = o > m ? o : m;
                }
                if (lane == j) myout = 8191 - (int)(m & 0x1FFFULL);
                if (k == m) k = 0ULL;
            }
            if (lane < KK) out[(size_t)i * KK + lane] = myout;
        }
    } else {
        // rare: fewer than K uniques -> sorted uniques + pad with own samples
        if (t == 0) {
            int sorted_u[KK];
            int cnt2 = 0;
            for (int mw = 0; mw < NN / 32 && cnt2 < KK; ++mw) {
                unsigned b = mask[mw];
                while (b && cnt2 < KK) {
                    int bit = __ffs(b) - 1;
                    b &= b - 1;
                    sorted_u[cnt2++] = mw * 32 + bit;
                }
            }
            for (int j = 0; j < KK; ++j) {
                int v;
                if (j < nu) {
                    v = sorted_u[j];
                } else {
                    int idx = j - nu;
                    if (idx > KK - 1) idx = KK - 1;
                    v = cs[(size_t)i * KK + idx];
                }
                out[(size_t)i * KK + j] = v;
            }
        }
    }
}

extern "C" void kernel_launch(void* const* d_in, const int* in_sizes, int n_in,
                              void* d_out, int out_size, void* d_ws, size_t ws_size,
                              hipStream_t stream)
{
    const float* x   = (const float*)d_in[0];
    const float* adj = (const float*)d_in[1];
    const int*   cs  = (const int*)d_in[2];
    int* out = (int*)d_out;
    int* cnt = WS_CNT(d_ws);
    int* nbr = WS_NBR(d_ws);

    hipMemsetAsync(cnt, 0, NN * sizeof(int), stream);
    adj_scan_kernel<<<SCAN_BLOCKS, 256, 0, stream>>>(
        reinterpret_cast<const uint4*>(adj), cnt, nbr);
    select_kernel<<<NN, 256, 0, stream>>>(x, cs, cnt, nbr, out);
}

// Round 5
// 167.348 us; speedup vs baseline: 1.2622x; 1.2622x over previous
//
#include <hip/hip_runtime.h>
#include <math.h>

// Problem constants (match reference file)
#define NN   8192   // nodes
#define DF   64     // feature dim
#define KK   16     // k samples
#define DEG  32     // max neighbors
#define MAXNBR (DEG + 1)     // self + neighbors (row has <= 32 ones)
#define SLOTS 3              // 256 threads * 3 >= 33*16 = 528 candidates

// ---- one block (4 waves) per node: scan row, gather, dedup, sims, top-K ----
__global__ __launch_bounds__(256, 4)
void fused_kernel(const float* __restrict__ x,
                  const uint4* __restrict__ adj4,
                  const int*   __restrict__ cs,
                  int*         __restrict__ out)
{
    const int i    = blockIdx.x;           // node id
    const int t    = threadIdx.x;
    const int w    = t >> 6;
    const int lane = t & 63;

    __shared__ unsigned mask[NN / 32];                 // 1 KB dedup bitmap
    __shared__ int nbrs[MAXNBR];
    __shared__ int nnbr;
    __shared__ unsigned long long wkeys[4 * KK];       // per-wave top-16s
    __shared__ int nu_sh;

    // ---- phase A: init ----
    for (int m = t; m < NN / 32; m += 256) mask[m] = 0u;
    if (t == 0) { nbrs[0] = i; nnbr = 1; nu_sh = 0; }
    __syncthreads();                                   // barrier 1

    // ---- phase B: scan row i — 2048 uint4s, 8 per thread, all 8 in flight ----
    const uint4* __restrict__ row4 = adj4 + (size_t)i * (NN / 4);
    uint4 v[8];
    #pragma unroll
    for (int u = 0; u < 8; ++u) v[u] = row4[t + 256 * u];   // coalesced, batched
    #pragma unroll
    for (int u = 0; u < 8; ++u) {
        if ((v[u].x | v[u].y | v[u].z | v[u].w) != 0u) {    // 1.0f == 0x3F800000
            const int base = 4 * (t + 256 * u);
            const unsigned e[4] = {v[u].x, v[u].y, v[u].z, v[u].w};
            #pragma unroll
            for (int c2 = 0; c2 < 4; ++c2) {
                if (e[c2] != 0u) {
                    int s = atomicAdd(&nnbr, 1);
                    if (s < MAXNBR) nbrs[s] = base + c2;
                }
            }
        }
    }
    __syncthreads();                                   // barrier 2

    const int M = min(nnbr, MAXNBR);
    const int total = M * KK;                          // <= 528
    const float* __restrict__ xr = x + (size_t)i * DF; // block-uniform -> SGPRs

    // ---- phase C: gather candidates, dedup via shared bitmap ----
    int  vals[SLOTS];
    bool valid[SLOTS];
    #pragma unroll
    for (int r = 0; r < SLOTS; ++r) {
        valid[r] = false;
        vals[r]  = 0;
        int q = t + 256 * r;
        if (q < total) {
            int node = nbrs[q >> 4];
            int vv = cs[(size_t)node * KK + (q & 15)];
            unsigned bit = 1u << (vv & 31);
            unsigned old = atomicOr(&mask[vv >> 5], bit);
            if (!(old & bit)) { valid[r] = true; vals[r] = vv; }
        }
    }

    // unique count: wave sum -> LDS add
    int myc = 0;
    #pragma unroll
    for (int r = 0; r < SLOTS; ++r) myc += valid[r] ? 1 : 0;
    #pragma unroll
    for (int off = 32; off; off >>= 1) myc += __shfl_xor(myc, off);
    if (lane == 0) atomicAdd(&nu_sh, myc);

    // ---- phase D: sims (strict sequential FMA chain — bit-matches BLAS k-loop) ----
    unsigned long long keys[SLOTS];
    #pragma unroll
    for (int r = 0; r < SLOTS; ++r) {
        unsigned long long key = 0ULL;
        if (valid[r]) {
            const float4* xc4 = reinterpret_cast<const float4*>(x + (size_t)vals[r] * DF);
            float4 xv[DF / 4];
            #pragma unroll
            for (int d4 = 0; d4 < DF / 4; ++d4) xv[d4] = xc4[d4];   // all 16 in flight
            float acc = 0.f;
            #pragma unroll
            for (int d4 = 0; d4 < DF / 4; ++d4) {
                acc = fmaf(xr[4 * d4 + 0], xv[d4].x, acc);
                acc = fmaf(xr[4 * d4 + 1], xv[d4].y, acc);
                acc = fmaf(xr[4 * d4 + 2], xv[d4].z, acc);
                acc = fmaf(xr[4 * d4 + 3], xv[d4].w, acc);
            }
            unsigned fb = __float_as_uint(acc);
            fb = (fb & 0x80000000u) ? ~fb : (fb | 0x80000000u);   // order-preserving
            key = ((unsigned long long)fb << 13) |
                  (unsigned long long)(unsigned)(8191 - vals[r]);
        }
        keys[r] = key;
    }

    // ---- phase E: per-wave top-16 (pure shuffles, no barriers) ----
    for (int j = 0; j < KK; ++j) {
        unsigned long long m = 0ULL;
        #pragma unroll
        for (int r = 0; r < SLOTS; ++r) m = keys[r] > m ? keys[r] : m;
        #pragma unroll
        for (int off = 32; off; off >>= 1) {
            unsigned long long o = __shfl_xor(m, off);
            m = o > m ? o : m;
        }
        if (lane == 0) wkeys[w * KK + j] = m;
        #pragma unroll
        for (int r = 0; r < SLOTS; ++r)
            if (keys[r] == m) keys[r] = 0ULL;   // values unique -> safe clear
    }
    __syncthreads();                                   // barrier 3

    // ---- phase F: wave 0 merges 64 keys; 16 shuffle-argmax rounds ----
    const int nu = nu_sh;
    if (nu >= KK) {
        if (w == 0) {
            unsigned long long k = wkeys[lane];        // 64 keys, one per lane
            int myout = 0;
            for (int j = 0; j < KK; ++j) {
                unsigned long long m = k;
                #pragma unroll
                for (int off = 32; off; off >>= 1) {
                    unsigned long long o = __shfl_xor(m, off);
                    m = o > m ? o : m;
                }
                if (lane == j) myout = 8191 - (int)(m & 0x1FFFULL);
                if (k == m) k = 0ULL;
            }
            if (lane < KK) out[(size_t)i * KK + lane] = myout;
        }
    } else {
        // rare: fewer than K uniques -> sorted uniques + pad with own samples
        if (t == 0) {
            int sorted_u[KK];
            int cnt2 = 0;
            for (int mw = 0; mw < NN / 32 && cnt2 < KK; ++mw) {
                unsigned b = mask[mw];
                while (b && cnt2 < KK) {
                    int bit = __ffs(b) - 1;
                    b &= b - 1;
                    sorted_u[cnt2++] = mw * 32 + bit;
                }
            }
            for (int j = 0; j < KK; ++j) {
                int vv;
                if (j < nu) {
                    vv = sorted_u[j];
                } else {
                    int idx = j - nu;
                    if (idx > KK - 1) idx = KK - 1;
                    vv = cs[(size_t)i * KK + idx];
                }
                out[(size_t)i * KK + j] = vv;
            }
        }
    }
}

extern "C" void kernel_launch(void* const* d_in, const int* in_sizes, int n_in,
                              void* d_out, int out_size, void* d_ws, size_t ws_size,
                              hipStream_t stream)
{
    const float* x   = (const float*)d_in[0];
    const float* adj = (const float*)d_in[1];
    const int*   cs  = (const int*)d_in[2];
    int* out = (int*)d_out;

    fused_kernel<<<NN, 256, 0, stream>>>(
        x, reinterpret_cast<const uint4*>(adj), cs, out);
}

// Round 7
// 166.718 us; speedup vs baseline: 1.2670x; 1.0038x over previous
//
#include <hip/hip_runtime.h>
#include <math.h>

// Problem constants (match reference file)
#define NN   8192   // nodes
#define DF   64     // feature dim
#define KK   16     // k samples
#define MAXNBR 33   // self + up to 32 neighbors (row has <= 32 ones)
#define NT   512    // threads per block
// lists: A = slots 0..7 (per-wave top-16s), B = slots 8..11 (merge round 1 out)
#define NSLOT 12

__device__ __forceinline__ unsigned long long kmax(unsigned long long a, unsigned long long b) {
    return a > b ? a : b;
}
__device__ __forceinline__ unsigned long long kmin(unsigned long long a, unsigned long long b) {
    return a > b ? b : a;
}

// full 64-lane bitonic sort, descending (mirror of standard ascending network)
__device__ __forceinline__ void sort64_desc(unsigned long long& kv, int lane) {
    #pragma unroll
    for (int k = 2; k <= 64; k <<= 1) {
        #pragma unroll
        for (int j = k >> 1; j > 0; j >>= 1) {
            unsigned long long o = __shfl_xor(kv, j);
            bool tmax = (((lane & j) == 0) != ((lane & k) != 0));
            kv = tmax ? kmax(kv, o) : kmin(kv, o);
        }
    }
}

// merge a 32-length bitonic sequence (lanes 0..31) into descending order
__device__ __forceinline__ void merge32_desc(unsigned long long& kv, int lane) {
    #pragma unroll
    for (int j = 16; j > 0; j >>= 1) {
        unsigned long long o = __shfl_xor(kv, j);
        kv = ((lane & j) == 0) ? kmax(kv, o) : kmin(kv, o);
    }
}

// ---- one block (8 waves) per node: scan row, gather, dedup, sims, sort-select ----
__global__ __launch_bounds__(NT, 4)
void fused_kernel(const float* __restrict__ x,
                  const uint4* __restrict__ adj4,
                  const int*   __restrict__ cs,
                  int*         __restrict__ out)
{
    const int i    = blockIdx.x;           // node id
    const int t    = threadIdx.x;
    const int w    = t >> 6;
    const int lane = t & 63;

    __shared__ unsigned mask[NN / 32];                 // 1 KB dedup bitmap
    __shared__ int nbrs[MAXNBR];
    __shared__ int nnbr;
    __shared__ int nu_sh;
    __shared__ unsigned long long lists[NSLOT * KK];   // sorted top-16 lists

    // ---- phase A: init ----
    if (t < NN / 32) mask[t] = 0u;                     // 256 words
    if (t == 0) { nbrs[0] = i; nnbr = 1; nu_sh = 0; }
    __syncthreads();                                   // barrier 1

    // ---- phase B: scan row i — 2048 uint4s, 4 per thread, all in flight ----
    const uint4* __restrict__ row4 = adj4 + (size_t)i * (NN / 4);
    uint4 v[4];
    #pragma unroll
    for (int u = 0; u < 4; ++u) v[u] = row4[t + NT * u];   // coalesced
    #pragma unroll
    for (int u = 0; u < 4; ++u) {
        if ((v[u].x | v[u].y | v[u].z | v[u].w) != 0u) {   // 1.0f == 0x3F800000
            const int base = 4 * (t + NT * u);
            const unsigned e[4] = {v[u].x, v[u].y, v[u].z, v[u].w};
            #pragma unroll
            for (int c2 = 0; c2 < 4; ++c2) {
                if (e[c2] != 0u) {
                    int s = atomicAdd(&nnbr, 1);
                    if (s < MAXNBR) nbrs[s] = base + c2;
                }
            }
        }
    }
    __syncthreads();                                   // barrier 2

    const int M = min(nnbr, MAXNBR);
    const int total = M * KK;                          // <= 528
    const float* __restrict__ xr = x + (size_t)i * DF; // block-uniform -> SGPRs

    // ---- phase C: gather candidates, dedup via shared bitmap ----
    // main slot: q = t (t < 512); overflow q = 512..527 on wave-1 lanes 0..15
    int  v0 = 0, v1 = 0;
    bool ok0 = false, ok1 = false;
    if (t < total) {
        v0 = cs[(size_t)nbrs[t >> 4] * KK + (t & 15)];
        unsigned bit = 1u << (v0 & 31);
        unsigned old = atomicOr(&mask[v0 >> 5], bit);
        ok0 = !(old & bit);
    }
    const int q2 = NT + (t - 64);                      // 512..527 for t=64..79
    if (t >= 64 && t < 80 && q2 < total) {
        v1 = cs[(size_t)nbrs[q2 >> 4] * KK + (q2 & 15)];
        unsigned bit = 1u << (v1 & 31);
        unsigned old = atomicOr(&mask[v1 >> 5], bit);
        ok1 = !(old & bit);
    }

    // unique count: wave sum -> LDS add
    int myc = (ok0 ? 1 : 0) + (ok1 ? 1 : 0);
    #pragma unroll
    for (int off = 32; off; off >>= 1) myc += __shfl_xor(myc, off);
    if (lane == 0) atomicAdd(&nu_sh, myc);

    // ---- phase D: sims (strict sequential FMA chain d=0..63 — bit-exact) ----
    unsigned long long k0 = 0ULL, k1 = 0ULL;
    #pragma unroll
    for (int which = 0; which < 2; ++which) {
        const bool ok  = which ? ok1 : ok0;
        const int  val = which ? v1  : v0;
        if (ok) {
            const float4* xc4 = reinterpret_cast<const float4*>(x + (size_t)val * DF);
            float acc = 0.f;
            #pragma unroll
            for (int h = 0; h < 2; ++h) {
                float4 xv[8];
                #pragma unroll
                for (int d4 = 0; d4 < 8; ++d4) xv[d4] = xc4[8 * h + d4];
                #pragma unroll
                for (int d4 = 0; d4 < 8; ++d4) {
                    acc = fmaf(xr[32 * h + 4 * d4 + 0], xv[d4].x, acc);
                    acc = fmaf(xr[32 * h + 4 * d4 + 1], xv[d4].y, acc);
                    acc = fmaf(xr[32 * h + 4 * d4 + 2], xv[d4].z, acc);
                    acc = fmaf(xr[32 * h + 4 * d4 + 3], xv[d4].w, acc);
                }
            }
            unsigned fb = __float_as_uint(acc);
            fb = (fb & 0x80000000u) ? ~fb : (fb | 0x80000000u);   // order-preserving
            unsigned long long key = ((unsigned long long)fb << 13) |
                                     (unsigned long long)(unsigned)(8191 - val);
            if (which) k1 = key; else k0 = key;
        }
    }

    // ---- phase E: per-wave descending bitonic sort; wave 1 folds in overflow ----
    sort64_desc(k0, lane);
    if (w == 1) {
        sort64_desc(k1, lane);
        // in-register merge of the two top-16s: lanes 0..15 = k0, 16..31 = k1 reversed
        unsigned long long o = __shfl(k1, (31 - lane) & 63);
        unsigned long long kk = (lane < 16) ? k0 : ((lane < 32) ? o : 0ULL);
        merge32_desc(kk, lane);
        k0 = kk;
    }
    if (lane < KK) lists[w * KK + lane] = k0;          // A-slots 0..7
    __syncthreads();                                   // barrier 3

    // merge two sorted-desc-16 lists (a,b) -> sorted-desc top-16 into dst
    #define MERGE2(dst, a, b)                                                   \
    {                                                                           \
        unsigned long long kk;                                                  \
        if (lane < 16)      kk = lists[(a) * KK + lane];                        \
        else if (lane < 32) kk = lists[(b) * KK + (31 - lane)];                 \
        else                kk = 0ULL;                                          \
        merge32_desc(kk, lane);                                                 \
        if (lane < 16) lists[(dst) * KK + lane] = kk;                           \
    }

    // ---- phase F: race-free ping-pong merge tree 8 -> 4 -> 2 -> 1 ----
    if (w < 4) MERGE2(8 + w, 2 * w, 2 * w + 1)         // read A0..A7, write B8..B11
    __syncthreads();                                   // barrier 4
    if (w < 2) MERGE2(w, 8 + 2 * w, 9 + 2 * w)         // read B8..B11, write A0..A1
    __syncthreads();                                   // barrier 5

    const int nu = nu_sh;
    if (w == 0) {
        // final merge of A0, A1 in registers; output directly
        unsigned long long kk;
        if (lane < 16)      kk = lists[0 * KK + lane];
        else if (lane < 32) kk = lists[1 * KK + (31 - lane)];
        else                kk = 0ULL;
        merge32_desc(kk, lane);
        if (nu >= KK && lane < KK)
            out[(size_t)i * KK + lane] = 8191 - (int)(kk & 0x1FFFULL);
    }

    // rare: fewer than K uniques -> sorted uniques + pad with own samples
    if (nu < KK && t == 0) {
        int sorted_u[KK];
        int cnt2 = 0;
        for (int mw = 0; mw < NN / 32 && cnt2 < KK; ++mw) {
            unsigned b = mask[mw];
            while (b && cnt2 < KK) {
                int bit = __ffs(b) - 1;
                b &= b - 1;
                sorted_u[cnt2++] = mw * 32 + bit;
            }
        }
        for (int j = 0; j < KK; ++j) {
            int vv;
            if (j < nu) {
                vv = sorted_u[j];
            } else {
                int idx = j - nu;
                if (idx > KK - 1) idx = KK - 1;
                vv = cs[(size_t)i * KK + idx];
            }
            out[(size_t)i * KK + j] = vv;
        }
    }
    #undef MERGE2
}

extern "C" void kernel_launch(void* const* d_in, const int* in_sizes, int n_in,
                              void* d_out, int out_size, void* d_ws, size_t ws_size,
                              hipStream_t stream)
{
    const float* x   = (const float*)d_in[0];
    const float* adj = (const float*)d_in[1];
    const int*   cs  = (const int*)d_in[2];
    int* out = (int*)d_out;

    fused_kernel<<<NN, NT, 0, stream>>>(
        x, reinterpret_cast<const uint4*>(adj), cs, out);
}